// Round 21
// baseline (149.074 us; speedup 1.0000x reference)
//
#include <hip/hip_runtime.h>
#include <hip/hip_bf16.h>

#define NEV 131072
#define NF 128
#define NG 64
#define KIN 192      // NF + NG
#define NH 512
#define NOUT 256     // N_BRANCHES * NF
#define BM 128
#define NT 512
#define TILES 4
#define NPERS (NEV / (BM * TILES))   // 256 = 1 block/CU
#define LDS128 131072

typedef __bf16 bf16x8 __attribute__((ext_vector_type(8)));
typedef __bf16 bf16x4 __attribute__((ext_vector_type(4)));
typedef float f32x4 __attribute__((ext_vector_type(4)));

// Swizzled LDS byte offsets: XOR (row&7)<<4 spreads rows across 16B slots.
__device__ __forceinline__ int a_off(int r, int cb) { return r * 384 + (cb ^ ((r & 7) << 4)); }
__device__ __forceinline__ int h_off(int r, int cb) { return r * 1024 + (cb ^ ((r & 7) << 4)); }

// ---- weight pre-pack into per-wave FRAGMENT ORDER (bf16), 1KB contiguous per
// wave fragment load. BYTE-IDENTICAL to rounds 3-20 (verified).
__global__ void pack_w(const float* __restrict__ W1, const float* __restrict__ W2,
                       __bf16* __restrict__ w1p, __bf16* __restrict__ w2p) {
    int t = blockIdx.x * blockDim.x + threadIdx.x;
    if (t < KIN * NH) {
        int j = t & 7;
        int lane = (t >> 3) & 63;
        int n = (t >> 9) & 3;
        int r = t >> 11;          // wc*6 + kk
        int kk = r % 6;
        int wc = r / 6;
        int lg = lane >> 4, lr = lane & 15;
        int k = kk * 32 + lg * 8 + j;
        int col = wc * 64 + n * 16 + lr;
        w1p[t] = (__bf16)W1[(size_t)k * NH + col];
    } else {
        int u = t - KIN * NH;
        if (u < NH * NOUT) {
            int j = u & 7;
            int lane = (u >> 3) & 63;
            int n = (u >> 9) & 1;
            int r = u >> 10;      // wc*16 + kk
            int kk = r & 15;
            int wc = r >> 4;
            int lg = lane >> 4, lr = lane & 15;
            int k = kk * 32 + lg * 8 + j;
            int col = wc * 32 + n * 16 + lr;
            w2p[u] = (__bf16)W2[(size_t)k * NOUT + col];
        }
    }
}

// ================= persistent: 256 blocks x 4 tiles of BM=128 ===============
// r20's compute core (BM=128, depth-2 weight queues, 256-reg budget) +
// persistence with IN-REGISTER next-tile staging. Register fit by phase:
// GEMM1 233 (no staging live - issued AFTER GEMM1), epi1 128+48+20=196,
// GEMM2 64+32+24+48+25=193, all < 256. Staging is xv[8]+gv[4]=48 regs (the
// gather copy xs is dropped: commit re-derives p!=e lanes via exec-masked
// fresh load - execz-skipped for identity idx). 3 of 4 stages overlap
// epi1+GEMM2 (~5000cy >> 900cy gather chain).
__global__ __launch_bounds__(NT)
__attribute__((amdgpu_waves_per_eu(2, 2))) void fused_pers(
        const float* __restrict__ x, const float* __restrict__ gf,
        const __bf16* __restrict__ w1p, const float* __restrict__ b1,
        const __bf16* __restrict__ w2p, const float* __restrict__ b2,
        const int* __restrict__ idx, float* __restrict__ out) {
    extern __shared__ __align__(16) unsigned char smem[];  // A [0,48K) overlaid by h [0,128K)

    const int tid = threadIdx.x;
    const int wc = tid >> 6;           // wave = col-group 0..7
    const int lane = tid & 63;
    const int lg = lane >> 4;
    const int lr = lane & 15;

    const f32x4* x4 = (const f32x4*)x;
    const f32x4* g4 = (const f32x4*)gf;
    f32x4* o4 = (f32x4*)out;
    const int xr = tid >> 5, xc = tid & 31;   // x staging: rows xr+16s (s<8)
    const int gr = tid >> 4, gc = tid & 15;   // gf staging: rows gr+32s (s<4)

    int row0 = blockIdx.x * (BM * TILES);

    // ---- prologue: stage tile 0 directly to LDS (r18 path) + W1 q0/q1
    bf16x8 bq0[4], bq1[4];
    {
        const __bf16* wp = w1p;
        asm volatile("" : "+s"(wp));
#pragma unroll
        for (int n = 0; n < 4; ++n)
            bq0[n] = *(const bf16x8*)(wp + (size_t)((wc * 6 + 0) * 4 + n) * 512 + lane * 8);
#pragma unroll
        for (int n = 0; n < 4; ++n)
            bq1[n] = *(const bf16x8*)(wp + (size_t)((wc * 6 + 1) * 4 + n) * 512 + lane * 8);
    }
#pragma unroll
    for (int q = tid; q < BM * (NF / 4); q += NT) {
        int r = q >> 5, c4 = q & 31;
        int e = row0 + r;
        int p = idx[e];
        f32x4 v = x4[(size_t)e * 32 + c4];
        __builtin_nontemporal_store(v, &o4[(size_t)e * 32 + c4]);   // out[0:NEV] = x
        f32x4 vs = v;
        if (p != e) vs = x4[(size_t)p * 32 + c4];
        bf16x4 tb = {(__bf16)vs[0], (__bf16)vs[1], (__bf16)vs[2], (__bf16)vs[3]};
        *(bf16x4*)(smem + a_off(r, c4 * 8)) = tb;
    }
#pragma unroll
    for (int q = tid; q < BM * (NG / 4); q += NT) {
        int r = q >> 4, c4 = q & 15;
        int e = row0 + r;
        int p = idx[e] & (NEV - 1);
        f32x4 vs = g4[(size_t)p * 16 + c4];
        bf16x4 tb = {(__bf16)vs[0], (__bf16)vs[1], (__bf16)vs[2], (__bf16)vs[3]};
        *(bf16x4*)(smem + a_off(r, 256 + c4 * 8)) = tb;
    }
    __syncthreads();

    f32x4 xv[8], gv[4];                       // staging registers (48)

    for (int t = 0; t < TILES; ++t) {
        // ---- GEMM1 (operand-swapped), depth-2 W1 queue
        f32x4 acc1T[4][8] = {};
#pragma unroll
        for (int kk = 0; kk < KIN / 32; ++kk) {
            bf16x8 bq2[4];
            if (kk + 2 < KIN / 32) {
                const __bf16* wp = w1p;
                asm volatile("" : "+s"(wp));
#pragma unroll
                for (int n = 0; n < 4; ++n)
                    bq2[n] = *(const bf16x8*)(wp + (size_t)((wc * 6 + kk + 2) * 4 + n) * 512 + lane * 8);
            }
            int kbyte = kk * 64 + lg * 16;
            bf16x8 a[8];
#pragma unroll
            for (int m = 0; m < 8; ++m)
                a[m] = *(const bf16x8*)(smem + a_off(m * 16 + lr, kbyte));
            __builtin_amdgcn_s_setprio(1);
#pragma unroll
            for (int n = 0; n < 4; ++n)
#pragma unroll
                for (int m = 0; m < 8; ++m)
                    acc1T[n][m] = __builtin_amdgcn_mfma_f32_16x16x32_bf16(bq0[n], a[m], acc1T[n][m], 0, 0, 0);
            __builtin_amdgcn_s_setprio(0);
#pragma unroll
            for (int n = 0; n < 4; ++n) { bq0[n] = bq1[n]; bq1[n] = bq2[n]; }
            __builtin_amdgcn_sched_barrier(0);
        }
        __syncthreads();   // A read done; h may overwrite [0,128K)

        // ---- issue next-tile gather loads; land during epi1 + GEMM2
        if (t + 1 < TILES) {
            int nrow = row0 + BM;
#pragma unroll
            for (int s = 0; s < 8; ++s) {
                int e = nrow + xr + 16 * s;
                xv[s] = x4[(size_t)e * 32 + xc];
            }
#pragma unroll
            for (int s = 0; s < 4; ++s) {
                int e = nrow + gr + 32 * s;
                int p = idx[e] & (NEV - 1);
                gv[s] = g4[(size_t)p * 16 + gc];
            }
        }

        // ---- epi1: bias + leaky_relu -> h bf16
#pragma unroll
        for (int n = 0; n < 4; ++n) {
            int c0 = wc * 64 + n * 16 + lg * 4;
            f32x4 bb = *(const f32x4*)(b1 + c0);
#pragma unroll
            for (int m = 0; m < 8; ++m) {
                int e = m * 16 + lr;
                bf16x4 tb;
#pragma unroll
                for (int i = 0; i < 4; ++i) {
                    float v = acc1T[n][m][i] + bb[i];
                    v = (v >= 0.f) ? v : 0.01f * v;
                    tb[i] = (__bf16)v;
                }
                *(bf16x4*)(smem + h_off(e, c0 * 2)) = tb;
            }
        }

        // W2 q0/q1 prefetch: lands during barrier
        bf16x8 cq0[2], cq1[2];
        {
            const __bf16* wp = w2p;
            asm volatile("" : "+s"(wp));
#pragma unroll
            for (int n = 0; n < 2; ++n)
                cq0[n] = *(const bf16x8*)(wp + (size_t)((wc * 16 + 0) * 2 + n) * 512 + lane * 8);
#pragma unroll
            for (int n = 0; n < 2; ++n)
                cq1[n] = *(const bf16x8*)(wp + (size_t)((wc * 16 + 1) * 2 + n) * 512 + lane * 8);
        }
        __syncthreads();   // h ready

        // ---- GEMM2 (operand-swapped), depth-2 W2 queue
        f32x4 acc2T[2][8] = {};
#pragma unroll
        for (int kk = 0; kk < NH / 32; ++kk) {
            bf16x8 cq2[2];
            if (kk + 2 < NH / 32) {
                const __bf16* wp = w2p;
                asm volatile("" : "+s"(wp));
#pragma unroll
                for (int n = 0; n < 2; ++n)
                    cq2[n] = *(const bf16x8*)(wp + (size_t)((wc * 16 + kk + 2) * 2 + n) * 512 + lane * 8);
            }
            int kbyte = kk * 64 + lg * 16;
            bf16x8 a2[8];
#pragma unroll
            for (int m = 0; m < 8; ++m)
                a2[m] = *(const bf16x8*)(smem + h_off(m * 16 + lr, kbyte));
            __builtin_amdgcn_s_setprio(1);
#pragma unroll
            for (int n = 0; n < 2; ++n)
#pragma unroll
                for (int m = 0; m < 8; ++m)
                    acc2T[n][m] = __builtin_amdgcn_mfma_f32_16x16x32_bf16(cq0[n], a2[m], acc2T[n][m], 0, 0, 0);
            __builtin_amdgcn_s_setprio(0);
#pragma unroll
            for (int n = 0; n < 2; ++n) { cq0[n] = cq1[n]; cq1[n] = cq2[n]; }
            __builtin_amdgcn_sched_barrier(0);
        }
        __syncthreads();   // h read done -> A region [0,48K) free

        // ---- commit next-tile A (+fused x->out copy); gather lanes re-load
        if (t + 1 < TILES) {
            int nrow = row0 + BM;
#pragma unroll
            for (int s = 0; s < 8; ++s) {
                int r = xr + 16 * s;
                int e = nrow + r;
                __builtin_nontemporal_store(xv[s], &o4[(size_t)e * 32 + xc]);  // out[0:NEV]=x
                int p = idx[e];                       // L1/L2-hot reload
                f32x4 vs = xv[s];
                if (p != e) vs = x4[(size_t)p * 32 + xc];   // execz-skipped normally
                bf16x4 tb = {(__bf16)vs[0], (__bf16)vs[1], (__bf16)vs[2], (__bf16)vs[3]};
                *(bf16x4*)(smem + a_off(r, xc * 8)) = tb;
            }
#pragma unroll
            for (int s = 0; s < 4; ++s) {
                int r = gr + 32 * s;
                bf16x4 tb = {(__bf16)gv[s][0], (__bf16)gv[s][1], (__bf16)gv[s][2], (__bf16)gv[s][3]};
                *(bf16x4*)(smem + a_off(r, 256 + gc * 8)) = tb;
            }
        }

        // ---- epi2: bias + branch-split, nt float4 stores, m-outer
        float* ob = out + ((size_t)NEV * (1 + (wc >> 2))) * NF;
#pragma unroll
        for (int m = 0; m < 8; ++m) {
            size_t ebase = (size_t)(row0 + m * 16 + lr) * NF;
#pragma unroll
            for (int n = 0; n < 2; ++n) {
                int col = wc * 32 + n * 16 + lg * 4;
                f32x4 bb = *(const f32x4*)(b2 + col);
                f32x4 v = acc2T[n][m] + bb;
                __builtin_nontemporal_store(v, (f32x4*)(ob + ebase + (col & 127)));
            }
        }

        // W1 q0/q1 reload for next tile (L2-hot, lands during barrier)
        if (t + 1 < TILES) {
            const __bf16* wp = w1p;
            asm volatile("" : "+s"(wp));
#pragma unroll
            for (int n = 0; n < 4; ++n)
                bq0[n] = *(const bf16x8*)(wp + (size_t)((wc * 6 + 0) * 4 + n) * 512 + lane * 8);
#pragma unroll
            for (int n = 0; n < 4; ++n)
                bq1[n] = *(const bf16x8*)(wp + (size_t)((wc * 6 + 1) * 4 + n) * 512 + lane * 8);
            __syncthreads();   // A(t+1) committed before next GEMM1
        }
        row0 += BM;
    }
}

// ================= round-5 monolith (fallback paths) =========================
template <bool TW>
__global__ __launch_bounds__(512, 2) void fused_mlp(
        const float* __restrict__ x, const float* __restrict__ gf,
        const __bf16* __restrict__ w1p, const float* __restrict__ W1f,
        const float* __restrict__ b1,
        const __bf16* __restrict__ w2p, const float* __restrict__ W2f,
        const float* __restrict__ b2,
        const int* __restrict__ idx,
        float* __restrict__ out) {
    __shared__ __align__(16) unsigned char smem[65536];

    const int tid = threadIdx.x;
    const int wid = tid >> 6;
    const int lane = tid & 63;
    const int lg = lane >> 4;
    const int lr = lane & 15;
    const int row0 = blockIdx.x * 64;

    bf16x8 b1r[KIN / 32][4];
#pragma unroll
    for (int kk = 0; kk < KIN / 32; ++kk)
#pragma unroll
        for (int n = 0; n < 4; ++n) {
            if (TW) {
                b1r[kk][n] = *(const bf16x8*)(w1p + (size_t)(((wid * 6 + kk) * 4 + n) * 64 + lane) * 8);
            } else {
                int col = wid * 64 + n * 16 + lr;
                const float* wcp = W1f + (size_t)(kk * 32 + lg * 8) * NH + col;
#pragma unroll
                for (int i = 0; i < 8; ++i) b1r[kk][n][i] = (__bf16)wcp[(size_t)i * NH];
            }
        }

    const f32x4* x4 = (const f32x4*)x;
    const f32x4* g4 = (const f32x4*)gf;
    f32x4* o4 = (f32x4*)out;
    for (int q = tid; q < 64 * (NF / 4); q += 512) {
        int r = q >> 5, c4 = q & 31;
        int e = row0 + r;
        int p = idx[e];
        f32x4 v = x4[(size_t)e * 32 + c4];
        __builtin_nontemporal_store(v, &o4[(size_t)e * 32 + c4]);
        f32x4 vs = v;
        if (p != e) vs = x4[(size_t)p * 32 + c4];
        bf16x4 tb = {(__bf16)vs[0], (__bf16)vs[1], (__bf16)vs[2], (__bf16)vs[3]};
        *(bf16x4*)(smem + a_off(r, c4 * 8)) = tb;
    }
    for (int q = tid; q < 64 * (NG / 4); q += 512) {
        int r = q >> 4, c4 = q & 15;
        int e = row0 + r;
        int p = idx[e] & (NEV - 1);
        f32x4 vs = g4[(size_t)p * 16 + c4];
        bf16x4 tb = {(__bf16)vs[0], (__bf16)vs[1], (__bf16)vs[2], (__bf16)vs[3]};
        *(bf16x4*)(smem + a_off(r, 256 + c4 * 8)) = tb;
    }
    __syncthreads();

    f32x4 acc1T[4][4] = {};
#pragma unroll
    for (int kk = 0; kk < KIN / 32; ++kk) {
        int kbyte = kk * 64 + lg * 16;
        bf16x8 a[4];
#pragma unroll
        for (int m = 0; m < 4; ++m)
            a[m] = *(const bf16x8*)(smem + a_off(m * 16 + lr, kbyte));
        __builtin_amdgcn_s_setprio(1);
#pragma unroll
        for (int n = 0; n < 4; ++n)
#pragma unroll
            for (int m = 0; m < 4; ++m)
                acc1T[n][m] = __builtin_amdgcn_mfma_f32_16x16x32_bf16(b1r[kk][n], a[m], acc1T[n][m], 0, 0, 0);
        __builtin_amdgcn_s_setprio(0);
    }

    bf16x8 b2r[NH / 32][2];
#pragma unroll
    for (int kk = 0; kk < NH / 32; ++kk)
#pragma unroll
        for (int n = 0; n < 2; ++n) {
            if (TW) {
                b2r[kk][n] = *(const bf16x8*)(w2p + (size_t)(((wid * 16 + kk) * 2 + n) * 64 + lane) * 8);
            } else {
                int col = wid * 32 + n * 16 + lr;
                const float* wcp = W2f + (size_t)(kk * 32 + lg * 8) * NOUT + col;
#pragma unroll
                for (int i = 0; i < 8; ++i) b2r[kk][n][i] = (__bf16)wcp[(size_t)i * NOUT];
            }
        }

    __syncthreads();

#pragma unroll
    for (int n = 0; n < 4; ++n) {
        f32x4 bb = *(const f32x4*)(b1 + wid * 64 + n * 16 + lg * 4);
        int cb = (wid * 64 + n * 16 + lg * 4) * 2;
#pragma unroll
        for (int m = 0; m < 4; ++m) {
            int e = m * 16 + lr;
            bf16x4 tb;
#pragma unroll
            for (int i = 0; i < 4; ++i) {
                float v = acc1T[n][m][i] + bb[i];
                v = (v >= 0.f) ? v : 0.01f * v;
                tb[i] = (__bf16)v;
            }
            *(bf16x4*)(smem + h_off(e, cb)) = tb;
        }
    }
    __syncthreads();

    f32x4 acc2T[2][4] = {};
#pragma unroll
    for (int kk = 0; kk < NH / 32; ++kk) {
        int kbyte = kk * 64 + lg * 16;
        bf16x8 a2[4];
#pragma unroll
        for (int m = 0; m < 4; ++m)
            a2[m] = *(const bf16x8*)(smem + h_off(m * 16 + lr, kbyte));
        __builtin_amdgcn_s_setprio(1);
#pragma unroll
        for (int n = 0; n < 2; ++n)
#pragma unroll
            for (int m = 0; m < 4; ++m)
                acc2T[n][m] = __builtin_amdgcn_mfma_f32_16x16x32_bf16(b2r[kk][n], a2[m], acc2T[n][m], 0, 0, 0);
        __builtin_amdgcn_s_setprio(0);
    }

    float* ob = out + ((size_t)NEV * (1 + (wid >> 2))) * NF;
#pragma unroll
    for (int m = 0; m < 4; ++m) {
        size_t ebase = (size_t)(row0 + m * 16 + lr) * NF;
#pragma unroll
        for (int n = 0; n < 2; ++n) {
            int col = wid * 32 + n * 16 + lg * 4;
            f32x4 bb = *(const f32x4*)(b2 + col);
            f32x4 v = acc2T[n][m] + bb;
            __builtin_nontemporal_store(v, (f32x4*)(ob + ebase + (col & 127)));
        }
    }
}

extern "C" void kernel_launch(void* const* d_in, const int* in_sizes, int n_in,
                              void* d_out, int out_size, void* d_ws, size_t ws_size,
                              hipStream_t stream) {
    const float* x  = (const float*)d_in[0];
    const float* gf = (const float*)d_in[1];
    const float* W1 = (const float*)d_in[2];
    const float* b1 = (const float*)d_in[3];
    const float* W2 = (const float*)d_in[4];
    const float* b2 = (const float*)d_in[5];
    const int*  idx = (const int*)d_in[6];
    float* out = (float*)d_out;

    const size_t wbytes = (size_t)(KIN * NH + NH * NOUT) * sizeof(__bf16);  // 458752
    int tot = KIN * NH + NH * NOUT;

    if (ws_size >= wbytes) {
        __bf16* w1p = (__bf16*)d_ws;
        __bf16* w2p = w1p + KIN * NH;
        pack_w<<<(tot + 511) / 512, 512, 0, stream>>>(W1, W2, w1p, w2p);
        hipError_t st = hipFuncSetAttribute(
            (const void*)fused_pers, hipFuncAttributeMaxDynamicSharedMemorySize, LDS128);
        if (st == hipSuccess) {
            fused_pers<<<NPERS, NT, LDS128, stream>>>(x, gf, w1p, b1, w2p, b2, idx, out);
        } else {
            fused_mlp<true><<<NEV / 64, 512, 0, stream>>>(x, gf, w1p, nullptr, b1,
                                                          w2p, nullptr, b2, idx, out);
        }
    } else {
        fused_mlp<false><<<NEV / 64, 512, 0, stream>>>(x, gf, nullptr, W1, b1,
                                                       nullptr, W2, b2, idx, out);
    }
}

// Round 22
// 100.978 us; speedup vs baseline: 1.4763x; 1.4763x over previous
//
#include <hip/hip_runtime.h>
#include <hip/hip_bf16.h>

#define NEV 131072
#define NF 128
#define NG 64
#define KIN 192      // NF + NG
#define NH 512
#define NOUT 256     // N_BRANCHES * NF
#define BM 128
#define NT 512
#define NBLK (NEV / BM)        // 1024
#define LDS128 131072

// sched_barrier mask: allow DS_READ(0x100)|SALU(0x4)|VALU(0x2) to cross;
// VMEM stays pinned (depth-2 weight queue can't balloon -> no spill).
#define SB_MASK 0x106

typedef __bf16 bf16x8 __attribute__((ext_vector_type(8)));
typedef __bf16 bf16x4 __attribute__((ext_vector_type(4)));
typedef float f32x4 __attribute__((ext_vector_type(4)));

// Swizzled LDS byte offsets: XOR (row&7)<<4 spreads rows across 16B slots.
__device__ __forceinline__ int a_off(int r, int cb) { return r * 384 + (cb ^ ((r & 7) << 4)); }
__device__ __forceinline__ int h_off(int r, int cb) { return r * 1024 + (cb ^ ((r & 7) << 4)); }

// ---- weight pre-pack into per-wave FRAGMENT ORDER (bf16), 1KB contiguous per
// wave fragment load. BYTE-IDENTICAL to rounds 3-20 (verified).
__global__ void pack_w(const float* __restrict__ W1, const float* __restrict__ W2,
                       __bf16* __restrict__ w1p, __bf16* __restrict__ w2p) {
    int t = blockIdx.x * blockDim.x + threadIdx.x;
    if (t < KIN * NH) {
        int j = t & 7;
        int lane = (t >> 3) & 63;
        int n = (t >> 9) & 3;
        int r = t >> 11;          // wc*6 + kk
        int kk = r % 6;
        int wc = r / 6;
        int lg = lane >> 4, lr = lane & 15;
        int k = kk * 32 + lg * 8 + j;
        int col = wc * 64 + n * 16 + lr;
        w1p[t] = (__bf16)W1[(size_t)k * NH + col];
    } else {
        int u = t - KIN * NH;
        if (u < NH * NOUT) {
            int j = u & 7;
            int lane = (u >> 3) & 63;
            int n = (u >> 9) & 1;
            int r = u >> 10;      // wc*16 + kk
            int kk = r & 15;
            int wc = r >> 4;
            int lg = lane >> 4, lr = lane & 15;
            int k = kk * 32 + lg * 8 + j;
            int col = wc * 32 + n * 16 + lr;
            w2p[u] = (__bf16)W2[(size_t)k * NOUT + col];
        }
    }
}

// ================= BM=128, 512 threads: 8 waves = 8 col-groups, all rows ====
// r20 (best 100.8us: depth-2 weight queues) with the r13-era sched_barrier(0)
// relaxed to SB_MASK: next-kk ds_reads may hoist into the current MFMA
// cluster (removes ~120-150cy cold-start LDS latency per kk x 22 iters x 4
// rounds ~= 5us), while VMEM stays pinned so the weight queue cannot be
// hoisted whole (the r10-r12 spill mode). Persistence retired for good
// (r4/r7/r19/r21: register staging always collides with GEMM peaks).
__global__ __launch_bounds__(NT)
__attribute__((amdgpu_waves_per_eu(2, 2))) void fused128(
        const float* __restrict__ x, const float* __restrict__ gf,
        const __bf16* __restrict__ w1p, const float* __restrict__ b1,
        const __bf16* __restrict__ w2p, const float* __restrict__ b2,
        const int* __restrict__ idx, float* __restrict__ out) {
    extern __shared__ __align__(16) unsigned char smem[];  // A [0,48K) overlaid by h [0,128K)

    const int tid = threadIdx.x;
    const int wc = tid >> 6;           // wave = col-group 0..7
    const int lane = tid & 63;
    const int lg = lane >> 4;
    const int lr = lane & 15;
    const int row0 = blockIdx.x * BM;

    // ---- GEMM1 kk=0,1 weight fragments: issued FIRST, hide under stage
    bf16x8 bq0[4], bq1[4];
    {
        const __bf16* wp = w1p;
        asm volatile("" : "+s"(wp));
#pragma unroll
        for (int n = 0; n < 4; ++n)
            bq0[n] = *(const bf16x8*)(wp + (size_t)((wc * 6 + 0) * 4 + n) * 512 + lane * 8);
#pragma unroll
        for (int n = 0; n < 4; ++n)
            bq1[n] = *(const bf16x8*)(wp + (size_t)((wc * 6 + 1) * 4 + n) * 512 + lane * 8);
    }

    // ---- stage A = [x | gf] bf16 into LDS (swizzled); fused x->out copy (nt)
    const f32x4* x4 = (const f32x4*)x;
    const f32x4* g4 = (const f32x4*)gf;
    f32x4* o4 = (f32x4*)out;
#pragma unroll
    for (int q = tid; q < BM * (NF / 4); q += NT) {
        int r = q >> 5, c4 = q & 31;
        int e = row0 + r;
        int p = idx[e];
        f32x4 v = x4[(size_t)e * 32 + c4];
        __builtin_nontemporal_store(v, &o4[(size_t)e * 32 + c4]);   // out[0:NEV] = x
        f32x4 vs = v;
        if (p != e) vs = x4[(size_t)p * 32 + c4];   // exec-masked gather
        bf16x4 tb = {(__bf16)vs[0], (__bf16)vs[1], (__bf16)vs[2], (__bf16)vs[3]};
        *(bf16x4*)(smem + a_off(r, c4 * 8)) = tb;
    }
#pragma unroll
    for (int q = tid; q < BM * (NG / 4); q += NT) {
        int r = q >> 4, c4 = q & 15;
        int e = row0 + r;
        int p = idx[e] & (NEV - 1);                 // parents_idxs % n_events
        f32x4 vs = g4[(size_t)p * 16 + c4];
        bf16x4 tb = {(__bf16)vs[0], (__bf16)vs[1], (__bf16)vs[2], (__bf16)vs[3]};
        *(bf16x4*)(smem + a_off(r, 256 + c4 * 8)) = tb;
    }
    __syncthreads();

    // ---- GEMM1 (operand-swapped): wave owns 64 hidden cols x ALL 128 rows.
    //      Flat a[8] ds_reads + DEPTH-2 rolling B prefetch.
    f32x4 acc1T[4][8] = {};
#pragma unroll
    for (int kk = 0; kk < KIN / 32; ++kk) {
        bf16x8 bq2[4];
        if (kk + 2 < KIN / 32) {
            const __bf16* wp = w1p;
            asm volatile("" : "+s"(wp));
#pragma unroll
            for (int n = 0; n < 4; ++n)
                bq2[n] = *(const bf16x8*)(wp + (size_t)((wc * 6 + kk + 2) * 4 + n) * 512 + lane * 8);
        }
        int kbyte = kk * 64 + lg * 16;
        bf16x8 a[8];
#pragma unroll
        for (int m = 0; m < 8; ++m)
            a[m] = *(const bf16x8*)(smem + a_off(m * 16 + lr, kbyte));
        __builtin_amdgcn_s_setprio(1);
#pragma unroll
        for (int n = 0; n < 4; ++n)
#pragma unroll
            for (int m = 0; m < 8; ++m)
                acc1T[n][m] = __builtin_amdgcn_mfma_f32_16x16x32_bf16(bq0[n], a[m], acc1T[n][m], 0, 0, 0);
        __builtin_amdgcn_s_setprio(0);
#pragma unroll
        for (int n = 0; n < 4; ++n) { bq0[n] = bq1[n]; bq1[n] = bq2[n]; }
        __builtin_amdgcn_sched_barrier(SB_MASK);   // VMEM pinned; ds_reads may cross
    }

    // ---- GEMM2 kk=0,1 weight fragments: issue before barrier, hide under epi1
    bf16x8 cq0[2], cq1[2];
    {
        const __bf16* wp = w2p;
        asm volatile("" : "+s"(wp));
#pragma unroll
        for (int n = 0; n < 2; ++n)
            cq0[n] = *(const bf16x8*)(wp + (size_t)((wc * 16 + 0) * 2 + n) * 512 + lane * 8);
#pragma unroll
        for (int n = 0; n < 2; ++n)
            cq1[n] = *(const bf16x8*)(wp + (size_t)((wc * 16 + 1) * 2 + n) * 512 + lane * 8);
    }
    __syncthreads();   // A fully read; smem becomes h (128KB)

    // ---- epi1: bias + leaky_relu -> h bf16 (vectorized ds_write_b64)
#pragma unroll
    for (int n = 0; n < 4; ++n) {
        int c0 = wc * 64 + n * 16 + lg * 4;
        f32x4 bb = *(const f32x4*)(b1 + c0);
#pragma unroll
        for (int m = 0; m < 8; ++m) {
            int e = m * 16 + lr;
            bf16x4 tb;
#pragma unroll
            for (int i = 0; i < 4; ++i) {
                float v = acc1T[n][m][i] + bb[i];
                v = (v >= 0.f) ? v : 0.01f * v;
                tb[i] = (__bf16)v;
            }
            *(bf16x4*)(smem + h_off(e, c0 * 2)) = tb;
        }
    }
    __syncthreads();   // h ready

    // ---- GEMM2 (operand-swapped): wave owns 32 out cols x ALL 128 rows.
    //      Flat a2[8] ds_reads + DEPTH-2 rolling prefetch (16 kk iterations).
    f32x4 acc2T[2][8] = {};
#pragma unroll
    for (int kk = 0; kk < NH / 32; ++kk) {
        bf16x8 cq2[2];
        if (kk + 2 < NH / 32) {
            const __bf16* wp = w2p;
            asm volatile("" : "+s"(wp));
#pragma unroll
            for (int n = 0; n < 2; ++n)
                cq2[n] = *(const bf16x8*)(wp + (size_t)((wc * 16 + kk + 2) * 2 + n) * 512 + lane * 8);
        }
        int kbyte = kk * 64 + lg * 16;
        bf16x8 a2[8];
#pragma unroll
        for (int m = 0; m < 8; ++m)
            a2[m] = *(const bf16x8*)(smem + h_off(m * 16 + lr, kbyte));
        __builtin_amdgcn_s_setprio(1);
#pragma unroll
        for (int n = 0; n < 2; ++n)
#pragma unroll
            for (int m = 0; m < 8; ++m)
                acc2T[n][m] = __builtin_amdgcn_mfma_f32_16x16x32_bf16(cq0[n], a2[m], acc2T[n][m], 0, 0, 0);
        __builtin_amdgcn_s_setprio(0);
#pragma unroll
        for (int n = 0; n < 2; ++n) { cq0[n] = cq1[n]; cq1[n] = cq2[n]; }
        __builtin_amdgcn_sched_barrier(SB_MASK);   // VMEM pinned; ds_reads may cross
    }

    // ---- epi2: bias + branch-split, nt float4 stores, m-outer so both 64B
    //      halves of each 128B out-line issue back-to-back
    float* ob = out + ((size_t)NEV * (1 + (wc >> 2))) * NF;
#pragma unroll
    for (int m = 0; m < 8; ++m) {
        size_t ebase = (size_t)(row0 + m * 16 + lr) * NF;
#pragma unroll
        for (int n = 0; n < 2; ++n) {
            int col = wc * 32 + n * 16 + lg * 4;
            f32x4 bb = *(const f32x4*)(b2 + col);
            f32x4 v = acc2T[n][m] + bb;
            __builtin_nontemporal_store(v, (f32x4*)(ob + ebase + (col & 127)));
        }
    }
}

// ================= round-5 monolith (fallback paths) =========================
template <bool TW>
__global__ __launch_bounds__(512, 2) void fused_mlp(
        const float* __restrict__ x, const float* __restrict__ gf,
        const __bf16* __restrict__ w1p, const float* __restrict__ W1f,
        const float* __restrict__ b1,
        const __bf16* __restrict__ w2p, const float* __restrict__ W2f,
        const float* __restrict__ b2,
        const int* __restrict__ idx,
        float* __restrict__ out) {
    __shared__ __align__(16) unsigned char smem[65536];

    const int tid = threadIdx.x;
    const int wid = tid >> 6;
    const int lane = tid & 63;
    const int lg = lane >> 4;
    const int lr = lane & 15;
    const int row0 = blockIdx.x * 64;

    bf16x8 b1r[KIN / 32][4];
#pragma unroll
    for (int kk = 0; kk < KIN / 32; ++kk)
#pragma unroll
        for (int n = 0; n < 4; ++n) {
            if (TW) {
                b1r[kk][n] = *(const bf16x8*)(w1p + (size_t)(((wid * 6 + kk) * 4 + n) * 64 + lane) * 8);
            } else {
                int col = wid * 64 + n * 16 + lr;
                const float* wcp = W1f + (size_t)(kk * 32 + lg * 8) * NH + col;
#pragma unroll
                for (int i = 0; i < 8; ++i) b1r[kk][n][i] = (__bf16)wcp[(size_t)i * NH];
            }
        }

    const f32x4* x4 = (const f32x4*)x;
    const f32x4* g4 = (const f32x4*)gf;
    f32x4* o4 = (f32x4*)out;
    for (int q = tid; q < 64 * (NF / 4); q += 512) {
        int r = q >> 5, c4 = q & 31;
        int e = row0 + r;
        int p = idx[e];
        f32x4 v = x4[(size_t)e * 32 + c4];
        __builtin_nontemporal_store(v, &o4[(size_t)e * 32 + c4]);
        f32x4 vs = v;
        if (p != e) vs = x4[(size_t)p * 32 + c4];
        bf16x4 tb = {(__bf16)vs[0], (__bf16)vs[1], (__bf16)vs[2], (__bf16)vs[3]};
        *(bf16x4*)(smem + a_off(r, c4 * 8)) = tb;
    }
    for (int q = tid; q < 64 * (NG / 4); q += 512) {
        int r = q >> 4, c4 = q & 15;
        int e = row0 + r;
        int p = idx[e] & (NEV - 1);
        f32x4 vs = g4[(size_t)p * 16 + c4];
        bf16x4 tb = {(__bf16)vs[0], (__bf16)vs[1], (__bf16)vs[2], (__bf16)vs[3]};
        *(bf16x4*)(smem + a_off(r, 256 + c4 * 8)) = tb;
    }
    __syncthreads();

    f32x4 acc1T[4][4] = {};
#pragma unroll
    for (int kk = 0; kk < KIN / 32; ++kk) {
        int kbyte = kk * 64 + lg * 16;
        bf16x8 a[4];
#pragma unroll
        for (int m = 0; m < 4; ++m)
            a[m] = *(const bf16x8*)(smem + a_off(m * 16 + lr, kbyte));
        __builtin_amdgcn_s_setprio(1);
#pragma unroll
        for (int n = 0; n < 4; ++n)
#pragma unroll
            for (int m = 0; m < 4; ++m)
                acc1T[n][m] = __builtin_amdgcn_mfma_f32_16x16x32_bf16(b1r[kk][n], a[m], acc1T[n][m], 0, 0, 0);
        __builtin_amdgcn_s_setprio(0);
    }

    bf16x8 b2r[NH / 32][2];
#pragma unroll
    for (int kk = 0; kk < NH / 32; ++kk)
#pragma unroll
        for (int n = 0; n < 2; ++n) {
            if (TW) {
                b2r[kk][n] = *(const bf16x8*)(w2p + (size_t)(((wid * 16 + kk) * 2 + n) * 64 + lane) * 8);
            } else {
                int col = wid * 32 + n * 16 + lr;
                const float* wcp = W2f + (size_t)(kk * 32 + lg * 8) * NOUT + col;
#pragma unroll
                for (int i = 0; i < 8; ++i) b2r[kk][n][i] = (__bf16)wcp[(size_t)i * NOUT];
            }
        }

    __syncthreads();

#pragma unroll
    for (int n = 0; n < 4; ++n) {
        f32x4 bb = *(const f32x4*)(b1 + wid * 64 + n * 16 + lg * 4);
        int cb = (wid * 64 + n * 16 + lg * 4) * 2;
#pragma unroll
        for (int m = 0; m < 4; ++m) {
            int e = m * 16 + lr;
            bf16x4 tb;
#pragma unroll
            for (int i = 0; i < 4; ++i) {
                float v = acc1T[n][m][i] + bb[i];
                v = (v >= 0.f) ? v : 0.01f * v;
                tb[i] = (__bf16)v;
            }
            *(bf16x4*)(smem + h_off(e, cb)) = tb;
        }
    }
    __syncthreads();

    f32x4 acc2T[2][4] = {};
#pragma unroll
    for (int kk = 0; kk < NH / 32; ++kk) {
        int kbyte = kk * 64 + lg * 16;
        bf16x8 a2[4];
#pragma unroll
        for (int m = 0; m < 4; ++m)
            a2[m] = *(const bf16x8*)(smem + h_off(m * 16 + lr, kbyte));
        __builtin_amdgcn_s_setprio(1);
#pragma unroll
        for (int n = 0; n < 2; ++n)
#pragma unroll
            for (int m = 0; m < 4; ++m)
                acc2T[n][m] = __builtin_amdgcn_mfma_f32_16x16x32_bf16(b2r[kk][n], a2[m], acc2T[n][m], 0, 0, 0);
        __builtin_amdgcn_s_setprio(0);
    }

    float* ob = out + ((size_t)NEV * (1 + (wid >> 2))) * NF;
#pragma unroll
    for (int m = 0; m < 4; ++m) {
        size_t ebase = (size_t)(row0 + m * 16 + lr) * NF;
#pragma unroll
        for (int n = 0; n < 2; ++n) {
            int col = wid * 32 + n * 16 + lg * 4;
            f32x4 bb = *(const f32x4*)(b2 + col);
            f32x4 v = acc2T[n][m] + bb;
            __builtin_nontemporal_store(v, (f32x4*)(ob + ebase + (col & 127)));
        }
    }
}

extern "C" void kernel_launch(void* const* d_in, const int* in_sizes, int n_in,
                              void* d_out, int out_size, void* d_ws, size_t ws_size,
                              hipStream_t stream) {
    const float* x  = (const float*)d_in[0];
    const float* gf = (const float*)d_in[1];
    const float* W1 = (const float*)d_in[2];
    const float* b1 = (const float*)d_in[3];
    const float* W2 = (const float*)d_in[4];
    const float* b2 = (const float*)d_in[5];
    const int*  idx = (const int*)d_in[6];
    float* out = (float*)d_out;

    const size_t wbytes = (size_t)(KIN * NH + NH * NOUT) * sizeof(__bf16);  // 458752
    int tot = KIN * NH + NH * NOUT;

    if (ws_size >= wbytes) {
        __bf16* w1p = (__bf16*)d_ws;
        __bf16* w2p = w1p + KIN * NH;
        pack_w<<<(tot + 511) / 512, 512, 0, stream>>>(W1, W2, w1p, w2p);
        hipError_t st = hipFuncSetAttribute(
            (const void*)fused128, hipFuncAttributeMaxDynamicSharedMemorySize, LDS128);
        if (st == hipSuccess) {
            fused128<<<NBLK, NT, LDS128, stream>>>(x, gf, w1p, b1, w2p, b2, idx, out);
        } else {
            fused_mlp<true><<<NEV / 64, 512, 0, stream>>>(x, gf, w1p, nullptr, b1,
                                                          w2p, nullptr, b2, idx, out);
        }
    } else {
        fused_mlp<false><<<NEV / 64, 512, 0, stream>>>(x, gf, nullptr, W1, b1,
                                                       nullptr, W2, b2, idx, out);
    }
}